// Round 2
// baseline (1857.845 us; speedup 1.0000x reference)
//
#include <hip/hip_runtime.h>
#include <cmath>

// Round 2: identical to round 1 (round-1 bench failed on GPU acquisition
// timeout, not on the kernel). See analysis for re-verified correctness.

#define N_    200000
#define NNZ_  2000000
#define G_    256

// ---------------- CSR build ----------------

__global__ __launch_bounds__(256) void hist_k(const int* __restrict__ lu, const int* __restrict__ ld,
                                              const int* __restrict__ l1, int* __restrict__ deg) {
    int e = blockIdx.x * 256 + threadIdx.x;
    if (e >= NNZ_) return;
    atomicAdd(&deg[lu[e]], 1);
    atomicAdd(&deg[N_ + ld[e]], 1);
    atomicAdd(&deg[2 * N_ + l1[e]], 1);
}

__global__ __launch_bounds__(256) void scan1_k(const int* __restrict__ in, int* __restrict__ out,
                                               int* __restrict__ bsum, int n) {
    __shared__ int lds[256];
    int tid = threadIdx.x;
    int base = blockIdx.x * 1024 + tid * 4;
    int v0 = (base + 0 < n) ? in[base + 0] : 0;
    int v1 = (base + 1 < n) ? in[base + 1] : 0;
    int v2 = (base + 2 < n) ? in[base + 2] : 0;
    int v3 = (base + 3 < n) ? in[base + 3] : 0;
    int s = v0 + v1 + v2 + v3;
    lds[tid] = s;
    __syncthreads();
    for (int off = 1; off < 256; off <<= 1) {
        int t = (tid >= off) ? lds[tid - off] : 0;
        __syncthreads();
        lds[tid] += t;
        __syncthreads();
    }
    int excl = lds[tid] - s;
    if (base + 0 < n) out[base + 0] = excl;
    if (base + 1 < n) out[base + 1] = excl + v0;
    if (base + 2 < n) out[base + 2] = excl + v0 + v1;
    if (base + 3 < n) out[base + 3] = excl + v0 + v1 + v2;
    if (tid == 255) bsum[blockIdx.x] = lds[255];
}

__global__ __launch_bounds__(256) void scan2_k(int* __restrict__ bsum, int nb, int* __restrict__ total_out) {
    __shared__ int lds[256];
    __shared__ int run_s;
    int tid = threadIdx.x;
    if (tid == 0) run_s = 0;
    __syncthreads();
    for (int c0 = 0; c0 < nb; c0 += 256) {
        int i = c0 + tid;
        int s = (i < nb) ? bsum[i] : 0;
        lds[tid] = s;
        __syncthreads();
        for (int off = 1; off < 256; off <<= 1) {
            int t = (tid >= off) ? lds[tid - off] : 0;
            __syncthreads();
            lds[tid] += t;
            __syncthreads();
        }
        int run = run_s;
        if (i < nb) bsum[i] = run + lds[tid] - s;
        __syncthreads();
        if (tid == 0) run_s = run + lds[255];
        __syncthreads();
    }
    if (tid == 0 && total_out) *total_out = run_s;
}

__global__ __launch_bounds__(256) void scan3_k(int* __restrict__ out, const int* __restrict__ bsum, int n) {
    int add = bsum[blockIdx.x];
    int base = blockIdx.x * 1024 + threadIdx.x * 4;
    #pragma unroll
    for (int k = 0; k < 4; ++k)
        if (base + k < n) out[base + k] += add;
}

__global__ __launch_bounds__(256) void scatter_k(const int* __restrict__ lu, const int* __restrict__ ld,
                                                 const int* __restrict__ l1, const float* __restrict__ l1v,
                                                 const int* __restrict__ rptr, int* __restrict__ cur,
                                                 int* __restrict__ cols, float* __restrict__ vcsr) {
    int e = blockIdx.x * 256 + threadIdx.x;
    if (e >= NNZ_) return;
    {
        int r = lu[e];
        int pos = rptr[r] + atomicAdd(&cur[r], 1);
        cols[pos] = lu[NNZ_ + e];
    }
    {
        int r = ld[e];
        int pos = rptr[N_ + r] + atomicAdd(&cur[N_ + r], 1);
        cols[pos] = ld[NNZ_ + e];
    }
    {
        int r = l1[e];
        int pos = rptr[2 * N_ + r] + atomicAdd(&cur[2 * N_ + r], 1);
        cols[pos] = l1[NNZ_ + e];
        vcsr[pos - 2 * NNZ_] = l1v[e];
    }
}

// ---------------- dense: h = x @ W (+ GAT scores) ----------------
// block 256 = (256/FO) rows x FO cols; W and x rows staged in LDS.

template <int FI, int FO, bool GAT>
__global__ __launch_bounds__(256) void gemm_k(const float* __restrict__ x, const float* __restrict__ W,
                                              const float* __restrict__ avs, const float* __restrict__ avd,
                                              float* __restrict__ h, float* __restrict__ ss,
                                              float* __restrict__ sd) {
    constexpr int ROWS = 256 / FO;
    constexpr int XS = FI + 1;  // pad to avoid LDS bank conflicts
    __shared__ float Ws[FI * FO];
    __shared__ float xs[ROWS * XS];
    int tid = threadIdx.x;
    for (int i = tid; i < FI * FO; i += 256) Ws[i] = W[i];
    int row0 = blockIdx.x * ROWS;
    for (int i = tid; i < ROWS * FI; i += 256) {
        int r = i / FI, k = i - r * FI;
        int gr = row0 + r;
        xs[r * XS + k] = (gr < N_) ? x[(size_t)gr * FI + k] : 0.f;
    }
    __syncthreads();
    int r = tid / FO, j = tid - (tid / FO) * FO;
    int grow = row0 + r;
    float acc = 0.f;
    #pragma unroll
    for (int k = 0; k < FI; ++k) acc = fmaf(xs[r * XS + k], Ws[k * FO + j], acc);
    if (grow < N_) h[(size_t)grow * FO + j] = acc;
    if constexpr (GAT) {
        float vs = acc * avs[j];
        float vd = acc * avd[j];
        #pragma unroll
        for (int m = FO / 2; m >= 1; m >>= 1) {
            vs += __shfl_xor(vs, m, FO);
            vd += __shfl_xor(vd, m, FO);
        }
        if (j == 0 && grow < N_) { ss[grow] = vs; sd[grow] = vd; }
    }
}

// ---------------- sparse row-gather ----------------
// FO/4 lanes per row, float4 per lane. GAT: w=exp(leakyrelu(ss[r]+sd[c])),
// Z in registers, normalize at the end (softmax shift-invariance; no segment_max needed).
// MODE: 0=write, 1=add, 2=add+relu (last branch of layer).

template <int FO, int MODE, bool GAT>
__global__ __launch_bounds__(256) void gather_k(const int* __restrict__ rptr, const int* __restrict__ cols,
                                                const float* __restrict__ vals, const float* __restrict__ h,
                                                const float* __restrict__ ss, const float* __restrict__ sd,
                                                float* __restrict__ xout, int valbase) {
    constexpr int LPR = FO / 4;
    constexpr int RPB = 256 / LPR;
    int tid = threadIdx.x;
    int lane = tid % LPR;
    int r = blockIdx.x * RPB + tid / LPR;
    if (r >= N_) return;
    int b = rptr[r], e = rptr[r + 1];
    float ax = 0.f, ay = 0.f, az = 0.f, aw = 0.f;
    float z = 0.f;
    float s_row = 0.f;
    if constexpr (GAT) s_row = ss[r];
    for (int p = b; p < e; ++p) {
        int c = cols[p];
        float wv;
        if constexpr (GAT) {
            float lg = s_row + sd[c];
            lg = lg > 0.f ? lg : 0.2f * lg;
            wv = __expf(lg);
            z += wv;
        } else {
            wv = vals[p - valbase];
        }
        const float4 hv = *reinterpret_cast<const float4*>(h + (size_t)c * FO + lane * 4);
        ax = fmaf(wv, hv.x, ax);
        ay = fmaf(wv, hv.y, ay);
        az = fmaf(wv, hv.z, az);
        aw = fmaf(wv, hv.w, aw);
    }
    if constexpr (GAT) {
        float inv = 1.f / (z + 1e-16f);
        ax *= inv; ay *= inv; az *= inv; aw *= inv;
    }
    float4* op = reinterpret_cast<float4*>(xout + (size_t)r * FO + lane * 4);
    if constexpr (MODE == 0) {
        *op = make_float4(ax, ay, az, aw);
    } else {
        float4 pv = *op;
        ax += pv.x; ay += pv.y; az += pv.z; aw += pv.w;
        if constexpr (MODE == 2) {
            ax = fmaxf(ax, 0.f); ay = fmaxf(ay, 0.f);
            az = fmaxf(az, 0.f); aw = fmaxf(aw, 0.f);
        }
        *op = make_float4(ax, ay, az, aw);
    }
}

// ---------------- pooling + softmax ----------------
// one block per graph; batch1 is sorted -> binary-search the row range.

__global__ __launch_bounds__(256) void pool_k(const float* __restrict__ x, const int* __restrict__ batch,
                                              float* __restrict__ out) {
    int g = blockIdx.x;
    __shared__ float part[256];
    __shared__ int sse[2];
    if (threadIdx.x < 2) {
        int target = g + threadIdx.x;
        int lo = 0, hi = N_;
        while (lo < hi) {
            int mid = (lo + hi) >> 1;
            if (batch[mid] < target) lo = mid + 1; else hi = mid;
        }
        sse[threadIdx.x] = lo;
    }
    __syncthreads();
    int s = sse[0], e = sse[1];
    int f = threadIdx.x % 8;
    float acc = 0.f;
    for (int i = s + threadIdx.x / 8; i < e; i += 32) acc += fabsf(x[(size_t)i * 8 + f]);
    part[threadIdx.x] = acc;
    __syncthreads();
    if (threadIdx.x < 8) {
        float t = 0.f;
        #pragma unroll
        for (int k = 0; k < 32; ++k) t += part[k * 8 + f];
        float cnt = (float)(e - s);
        part[f] = t / fmaxf(cnt, 1.0f);
    }
    __syncthreads();
    if (threadIdx.x == 0) {
        float m = part[0];
        for (int j = 1; j < 8; ++j) m = fmaxf(m, part[j]);
        float zs = 0.f;
        float ex[8];
        for (int j = 0; j < 8; ++j) { ex[j] = __expf(part[j] - m); zs += ex[j]; }
        for (int j = 0; j < 8; ++j) out[g * 8 + j] = ex[j] / zs;
    }
}

// ---------------- layer driver ----------------

template <int FI, int FO>
static void run_layer(const float* xin, float* xout, const float* pW, const float* uW,
                      const float* uas, const float* uad, const float* dW, const float* das,
                      const float* dad, float* H, float* SS, float* SD, const int* PTR,
                      const int* COLS, const float* VCSR, hipStream_t stream) {
    constexpr int ROWS = 256 / FO;
    int gblk = (N_ + ROWS - 1) / ROWS;
    constexpr int RPB = 256 / (FO / 4);
    int ablk = (N_ + RPB - 1) / RPB;
    // u branch (write)
    gemm_k<FI, FO, true><<<gblk, 256, 0, stream>>>(xin, uW, uas, uad, H, SS, SD);
    gather_k<FO, 0, true><<<ablk, 256, 0, stream>>>(PTR, COLS, nullptr, H, SS, SD, xout, 0);
    // d branch (add)
    gemm_k<FI, FO, true><<<gblk, 256, 0, stream>>>(xin, dW, das, dad, H, SS, SD);
    gather_k<FO, 1, true><<<ablk, 256, 0, stream>>>(PTR + N_, COLS, nullptr, H, SS, SD, xout, 0);
    // p branch (add + relu)
    gemm_k<FI, FO, false><<<gblk, 256, 0, stream>>>(xin, pW, nullptr, nullptr, H, nullptr, nullptr);
    gather_k<FO, 2, false><<<ablk, 256, 0, stream>>>(PTR + 2 * N_, COLS, VCSR, H, nullptr, nullptr,
                                                     xout, 2 * NNZ_);
}

extern "C" void kernel_launch(void* const* d_in, const int* in_sizes, int n_in, void* d_out,
                              int out_size, void* d_ws, size_t ws_size, hipStream_t stream) {
    (void)in_sizes; (void)n_in; (void)out_size; (void)ws_size;
    const float* x1     = (const float*)d_in[0];
    const int*   l1_idx = (const int*)d_in[29];
    const float* l1_val = (const float*)d_in[30];
    const int*   lu_idx = (const int*)d_in[31];
    const int*   ld_idx = (const int*)d_in[32];
    const int*   batch1 = (const int*)d_in[33];
    float* out = (float*)d_out;

    char* w = (char*)d_ws;
    size_t off = 0;
    auto alloc = [&](size_t bytes) -> char* {
        char* p = w + off;
        off = (off + bytes + 255) & ~(size_t)255;
        return p;
    };
    float* H    = (float*)alloc((size_t)N_ * 32 * 4);
    float* XA   = (float*)alloc((size_t)N_ * 32 * 4);
    float* XB   = (float*)alloc((size_t)N_ * 32 * 4);
    float* SS   = (float*)alloc((size_t)N_ * 4);
    float* SD   = (float*)alloc((size_t)N_ * 4);
    int*   PTR  = (int*)alloc((size_t)(3 * N_ + 1) * 4);
    int*   DEG  = (int*)alloc((size_t)3 * N_ * 4);
    int*   CUR  = (int*)alloc((size_t)3 * N_ * 4);
    int*   BSUM = (int*)alloc((size_t)1024 * 4);
    int*   COLS = (int*)alloc((size_t)3 * NNZ_ * 4);
    float* VCSR = (float*)alloc((size_t)NNZ_ * 4);

    // ---- CSR build (indices are layer-invariant: build once, reuse 4x) ----
    hipMemsetAsync(DEG, 0, (size_t)3 * N_ * 4, stream);
    hipMemsetAsync(CUR, 0, (size_t)3 * N_ * 4, stream);
    int ebl = (NNZ_ + 255) / 256;
    hist_k<<<ebl, 256, 0, stream>>>(lu_idx, ld_idx, l1_idx, DEG);
    int n3 = 3 * N_;
    int nb = (n3 + 1023) / 1024;
    scan1_k<<<nb, 256, 0, stream>>>(DEG, PTR, BSUM, n3);
    scan2_k<<<1, 256, 0, stream>>>(BSUM, nb, PTR + n3);
    scan3_k<<<nb, 256, 0, stream>>>(PTR, BSUM, n3);
    scatter_k<<<ebl, 256, 0, stream>>>(lu_idx, ld_idx, l1_idx, l1_val, PTR, CUR, COLS, VCSR);

    // ---- 4 SAN layers ----
    const float* W0[7] = {(const float*)d_in[1], (const float*)d_in[2], (const float*)d_in[3],
                          (const float*)d_in[4], (const float*)d_in[5], (const float*)d_in[6],
                          (const float*)d_in[7]};
    const float* W1[7] = {(const float*)d_in[8],  (const float*)d_in[9],  (const float*)d_in[10],
                          (const float*)d_in[11], (const float*)d_in[12], (const float*)d_in[13],
                          (const float*)d_in[14]};
    const float* W2[7] = {(const float*)d_in[15], (const float*)d_in[16], (const float*)d_in[17],
                          (const float*)d_in[18], (const float*)d_in[19], (const float*)d_in[20],
                          (const float*)d_in[21]};
    const float* W3[7] = {(const float*)d_in[22], (const float*)d_in[23], (const float*)d_in[24],
                          (const float*)d_in[25], (const float*)d_in[26], (const float*)d_in[27],
                          (const float*)d_in[28]};

    run_layer<64, 32>(x1, XA, W0[0], W0[1], W0[2], W0[3], W0[4], W0[5], W0[6],
                      H, SS, SD, PTR, COLS, VCSR, stream);
    run_layer<32, 32>(XA, XB, W1[0], W1[1], W1[2], W1[3], W1[4], W1[5], W1[6],
                      H, SS, SD, PTR, COLS, VCSR, stream);
    run_layer<32, 32>(XB, XA, W2[0], W2[1], W2[2], W2[3], W2[4], W2[5], W2[6],
                      H, SS, SD, PTR, COLS, VCSR, stream);
    run_layer<32, 8>(XA, XB, W3[0], W3[1], W3[2], W3[3], W3[4], W3[5], W3[6],
                     H, SS, SD, PTR, COLS, VCSR, stream);

    // ---- global mean pool of |x| + row softmax ----
    pool_k<<<G_, 256, 0, stream>>>(XB, batch1, out);
}

// Round 4
// 1552.161 us; speedup vs baseline: 1.1969x; 1.1969x over previous
//
#include <hip/hip_runtime.h>
#include <cmath>

// Round 4: identical to round 3 (round-3 bench failed on GPU acquisition
// timeout, not on the kernel). Ticket-scatter + per-layer fusion + x4
// unrolled gather loop; see round-3 analysis.

#define N_    200000
#define NNZ_  2000000
#define G_    256

// ---------------- CSR build ----------------

__global__ __launch_bounds__(256) void hist_k(const int* __restrict__ lu, const int* __restrict__ ld,
                                              const int* __restrict__ l1, int* __restrict__ deg,
                                              int* __restrict__ tick) {
    int i = blockIdx.x * 256 + threadIdx.x;
    if (i >= NNZ_ / 4) return;
    int e = i * 4;
    int4 ru = *reinterpret_cast<const int4*>(lu + e);
    int4 rd = *reinterpret_cast<const int4*>(ld + e);
    int4 rl = *reinterpret_cast<const int4*>(l1 + e);
    int4 t;
    t.x = atomicAdd(&deg[ru.x], 1);
    t.y = atomicAdd(&deg[ru.y], 1);
    t.z = atomicAdd(&deg[ru.z], 1);
    t.w = atomicAdd(&deg[ru.w], 1);
    *reinterpret_cast<int4*>(tick + e) = t;
    t.x = atomicAdd(&deg[N_ + rd.x], 1);
    t.y = atomicAdd(&deg[N_ + rd.y], 1);
    t.z = atomicAdd(&deg[N_ + rd.z], 1);
    t.w = atomicAdd(&deg[N_ + rd.w], 1);
    *reinterpret_cast<int4*>(tick + NNZ_ + e) = t;
    t.x = atomicAdd(&deg[2 * N_ + rl.x], 1);
    t.y = atomicAdd(&deg[2 * N_ + rl.y], 1);
    t.z = atomicAdd(&deg[2 * N_ + rl.z], 1);
    t.w = atomicAdd(&deg[2 * N_ + rl.w], 1);
    *reinterpret_cast<int4*>(tick + 2 * NNZ_ + e) = t;
}

__global__ __launch_bounds__(256) void scan1_k(const int* __restrict__ in, int* __restrict__ out,
                                               int* __restrict__ bsum, int n) {
    __shared__ int lds[256];
    int tid = threadIdx.x;
    int base = blockIdx.x * 1024 + tid * 4;
    int v0 = (base + 0 < n) ? in[base + 0] : 0;
    int v1 = (base + 1 < n) ? in[base + 1] : 0;
    int v2 = (base + 2 < n) ? in[base + 2] : 0;
    int v3 = (base + 3 < n) ? in[base + 3] : 0;
    int s = v0 + v1 + v2 + v3;
    lds[tid] = s;
    __syncthreads();
    for (int off = 1; off < 256; off <<= 1) {
        int t = (tid >= off) ? lds[tid - off] : 0;
        __syncthreads();
        lds[tid] += t;
        __syncthreads();
    }
    int excl = lds[tid] - s;
    if (base + 0 < n) out[base + 0] = excl;
    if (base + 1 < n) out[base + 1] = excl + v0;
    if (base + 2 < n) out[base + 2] = excl + v0 + v1;
    if (base + 3 < n) out[base + 3] = excl + v0 + v1 + v2;
    if (tid == 255) bsum[blockIdx.x] = lds[255];
}

__global__ __launch_bounds__(256) void scan2_k(int* __restrict__ bsum, int nb, int* __restrict__ total_out) {
    __shared__ int lds[256];
    __shared__ int run_s;
    int tid = threadIdx.x;
    if (tid == 0) run_s = 0;
    __syncthreads();
    for (int c0 = 0; c0 < nb; c0 += 256) {
        int i = c0 + tid;
        int s = (i < nb) ? bsum[i] : 0;
        lds[tid] = s;
        __syncthreads();
        for (int off = 1; off < 256; off <<= 1) {
            int t = (tid >= off) ? lds[tid - off] : 0;
            __syncthreads();
            lds[tid] += t;
            __syncthreads();
        }
        int run = run_s;
        if (i < nb) bsum[i] = run + lds[tid] - s;
        __syncthreads();
        if (tid == 0) run_s = run + lds[255];
        __syncthreads();
    }
    if (tid == 0 && total_out) *total_out = run_s;
}

__global__ __launch_bounds__(256) void scan3_k(int* __restrict__ out, const int* __restrict__ bsum, int n) {
    int add = bsum[blockIdx.x];
    int base = blockIdx.x * 1024 + threadIdx.x * 4;
    #pragma unroll
    for (int k = 0; k < 4; ++k)
        if (base + k < n) out[base + k] += add;
}

__global__ __launch_bounds__(256) void scatter_k(const int* __restrict__ lu, const int* __restrict__ ld,
                                                 const int* __restrict__ l1, const float* __restrict__ l1v,
                                                 const int* __restrict__ rptr, const int* __restrict__ tick,
                                                 int* __restrict__ cols, float* __restrict__ vcsr) {
    int i = blockIdx.x * 256 + threadIdx.x;
    if (i >= NNZ_ / 4) return;
    int e = i * 4;
    {
        int4 r = *reinterpret_cast<const int4*>(lu + e);
        int4 c = *reinterpret_cast<const int4*>(lu + NNZ_ + e);
        int4 t = *reinterpret_cast<const int4*>(tick + e);
        __builtin_nontemporal_store(c.x, &cols[rptr[r.x] + t.x]);
        __builtin_nontemporal_store(c.y, &cols[rptr[r.y] + t.y]);
        __builtin_nontemporal_store(c.z, &cols[rptr[r.z] + t.z]);
        __builtin_nontemporal_store(c.w, &cols[rptr[r.w] + t.w]);
    }
    {
        int4 r = *reinterpret_cast<const int4*>(ld + e);
        int4 c = *reinterpret_cast<const int4*>(ld + NNZ_ + e);
        int4 t = *reinterpret_cast<const int4*>(tick + NNZ_ + e);
        __builtin_nontemporal_store(c.x, &cols[rptr[N_ + r.x] + t.x]);
        __builtin_nontemporal_store(c.y, &cols[rptr[N_ + r.y] + t.y]);
        __builtin_nontemporal_store(c.z, &cols[rptr[N_ + r.z] + t.z]);
        __builtin_nontemporal_store(c.w, &cols[rptr[N_ + r.w] + t.w]);
    }
    {
        int4 r = *reinterpret_cast<const int4*>(l1 + e);
        int4 c = *reinterpret_cast<const int4*>(l1 + NNZ_ + e);
        int4 t = *reinterpret_cast<const int4*>(tick + 2 * NNZ_ + e);
        float4 v = *reinterpret_cast<const float4*>(l1v + e);
        int p0 = rptr[2 * N_ + r.x] + t.x;
        int p1 = rptr[2 * N_ + r.y] + t.y;
        int p2 = rptr[2 * N_ + r.z] + t.z;
        int p3 = rptr[2 * N_ + r.w] + t.w;
        __builtin_nontemporal_store(c.x, &cols[p0]);
        __builtin_nontemporal_store(c.y, &cols[p1]);
        __builtin_nontemporal_store(c.z, &cols[p2]);
        __builtin_nontemporal_store(c.w, &cols[p3]);
        __builtin_nontemporal_store(v.x, &vcsr[p0 - 2 * NNZ_]);
        __builtin_nontemporal_store(v.y, &vcsr[p1 - 2 * NNZ_]);
        __builtin_nontemporal_store(v.z, &vcsr[p2 - 2 * NNZ_]);
        __builtin_nontemporal_store(v.w, &vcsr[p3 - 2 * NNZ_]);
    }
}

// ---------------- fused dense: HU/HD/HP = x @ {uW,dW,pW} + GAT scores ----

template <int FI, int FO>
__global__ __launch_bounds__(256) void gemm3_k(const float* __restrict__ x,
                                               const float* __restrict__ uW, const float* __restrict__ uas,
                                               const float* __restrict__ uad,
                                               const float* __restrict__ dW, const float* __restrict__ das,
                                               const float* __restrict__ dad,
                                               const float* __restrict__ pW,
                                               float* __restrict__ HU, float* __restrict__ HD,
                                               float* __restrict__ HP,
                                               float* __restrict__ ssu, float* __restrict__ sdu,
                                               float* __restrict__ ssd, float* __restrict__ sdd) {
    constexpr int ROWS = 256 / FO;
    constexpr int XS = FI + 1;  // pad against LDS bank conflicts
    __shared__ float Wu[FI * FO], Wd[FI * FO], Wp[FI * FO];
    __shared__ float xs[ROWS * XS];
    int tid = threadIdx.x;
    for (int i = tid; i < FI * FO; i += 256) {
        Wu[i] = uW[i];
        Wd[i] = dW[i];
        Wp[i] = pW[i];
    }
    int row0 = blockIdx.x * ROWS;
    for (int i = tid; i < ROWS * FI; i += 256) {
        int r = i / FI, k = i - r * FI;
        int gr = row0 + r;
        xs[r * XS + k] = (gr < N_) ? x[(size_t)gr * FI + k] : 0.f;
    }
    __syncthreads();
    int r = tid / FO, j = tid - (tid / FO) * FO;
    int grow = row0 + r;
    float au = 0.f, ad = 0.f, ap = 0.f;
    #pragma unroll
    for (int k = 0; k < FI; ++k) {
        float xv = xs[r * XS + k];
        au = fmaf(xv, Wu[k * FO + j], au);
        ad = fmaf(xv, Wd[k * FO + j], ad);
        ap = fmaf(xv, Wp[k * FO + j], ap);
    }
    if (grow < N_) {
        HU[(size_t)grow * FO + j] = au;
        HD[(size_t)grow * FO + j] = ad;
        HP[(size_t)grow * FO + j] = ap;
    }
    float vsu = au * uas[j], vdu = au * uad[j];
    float vsd = ad * das[j], vdd = ad * dad[j];
    #pragma unroll
    for (int m = FO / 2; m >= 1; m >>= 1) {
        vsu += __shfl_xor(vsu, m, FO);
        vdu += __shfl_xor(vdu, m, FO);
        vsd += __shfl_xor(vsd, m, FO);
        vdd += __shfl_xor(vdd, m, FO);
    }
    if (j == 0 && grow < N_) {
        ssu[grow] = vsu; sdu[grow] = vdu;
        ssd[grow] = vsd; sdd[grow] = vdd;
    }
}

// ---------------- fused sparse gather (u + d + p in one pass) ----------

template <int FO, bool GAT>
__device__ __forceinline__ void edge_loop(const int* __restrict__ cols, const float* __restrict__ sdv,
                                          const float* __restrict__ vals, const float* __restrict__ H,
                                          int b, int e, int lane, float s_row, int vbase,
                                          float& ax, float& ay, float& az, float& aw, float& z) {
    int p = b;
    for (; p + 4 <= e; p += 4) {
        int c0 = cols[p], c1 = cols[p + 1], c2 = cols[p + 2], c3 = cols[p + 3];
        const float4 h0 = *reinterpret_cast<const float4*>(H + (size_t)c0 * FO + lane * 4);
        const float4 h1 = *reinterpret_cast<const float4*>(H + (size_t)c1 * FO + lane * 4);
        const float4 h2 = *reinterpret_cast<const float4*>(H + (size_t)c2 * FO + lane * 4);
        const float4 h3 = *reinterpret_cast<const float4*>(H + (size_t)c3 * FO + lane * 4);
        float w0, w1, w2, w3;
        if constexpr (GAT) {
            float g0 = s_row + sdv[c0];
            float g1 = s_row + sdv[c1];
            float g2 = s_row + sdv[c2];
            float g3 = s_row + sdv[c3];
            g0 = g0 > 0.f ? g0 : 0.2f * g0;
            g1 = g1 > 0.f ? g1 : 0.2f * g1;
            g2 = g2 > 0.f ? g2 : 0.2f * g2;
            g3 = g3 > 0.f ? g3 : 0.2f * g3;
            w0 = __expf(g0); w1 = __expf(g1); w2 = __expf(g2); w3 = __expf(g3);
            z += (w0 + w1) + (w2 + w3);
        } else {
            w0 = vals[p - vbase];
            w1 = vals[p - vbase + 1];
            w2 = vals[p - vbase + 2];
            w3 = vals[p - vbase + 3];
        }
        ax = fmaf(w0, h0.x, ax); ay = fmaf(w0, h0.y, ay);
        az = fmaf(w0, h0.z, az); aw = fmaf(w0, h0.w, aw);
        ax = fmaf(w1, h1.x, ax); ay = fmaf(w1, h1.y, ay);
        az = fmaf(w1, h1.z, az); aw = fmaf(w1, h1.w, aw);
        ax = fmaf(w2, h2.x, ax); ay = fmaf(w2, h2.y, ay);
        az = fmaf(w2, h2.z, az); aw = fmaf(w2, h2.w, aw);
        ax = fmaf(w3, h3.x, ax); ay = fmaf(w3, h3.y, ay);
        az = fmaf(w3, h3.z, az); aw = fmaf(w3, h3.w, aw);
    }
    for (; p < e; ++p) {
        int c = cols[p];
        const float4 hv = *reinterpret_cast<const float4*>(H + (size_t)c * FO + lane * 4);
        float wv;
        if constexpr (GAT) {
            float g = s_row + sdv[c];
            g = g > 0.f ? g : 0.2f * g;
            wv = __expf(g);
            z += wv;
        } else {
            wv = vals[p - vbase];
        }
        ax = fmaf(wv, hv.x, ax); ay = fmaf(wv, hv.y, ay);
        az = fmaf(wv, hv.z, az); aw = fmaf(wv, hv.w, aw);
    }
}

template <int FO>
__global__ __launch_bounds__(256) void gather3_k(const int* __restrict__ rptr, const int* __restrict__ cols,
                                                 const float* __restrict__ vcsr,
                                                 const float* __restrict__ HU, const float* __restrict__ HD,
                                                 const float* __restrict__ HP,
                                                 const float* __restrict__ ssu, const float* __restrict__ sdu,
                                                 const float* __restrict__ ssd, const float* __restrict__ sdd,
                                                 float* __restrict__ xout) {
    constexpr int LPR = FO / 4;
    constexpr int RPB = 256 / LPR;
    int tid = threadIdx.x;
    int lane = tid % LPR;
    int r = blockIdx.x * RPB + tid / LPR;
    if (r >= N_) return;
    float ox, oy, oz, ow;
    {   // u branch
        float ax = 0.f, ay = 0.f, az = 0.f, aw = 0.f, z = 0.f;
        edge_loop<FO, true>(cols, sdu, nullptr, HU, rptr[r], rptr[r + 1], lane, ssu[r], 0,
                            ax, ay, az, aw, z);
        float inv = 1.f / (z + 1e-16f);
        ox = ax * inv; oy = ay * inv; oz = az * inv; ow = aw * inv;
    }
    {   // d branch
        float ax = 0.f, ay = 0.f, az = 0.f, aw = 0.f, z = 0.f;
        edge_loop<FO, true>(cols, sdd, nullptr, HD, rptr[N_ + r], rptr[N_ + r + 1], lane, ssd[r], 0,
                            ax, ay, az, aw, z);
        float inv = 1.f / (z + 1e-16f);
        ox = fmaf(ax, inv, ox); oy = fmaf(ay, inv, oy);
        oz = fmaf(az, inv, oz); ow = fmaf(aw, inv, ow);
    }
    {   // p branch (sparse Laplacian values)
        float ax = 0.f, ay = 0.f, az = 0.f, aw = 0.f, z = 0.f;
        edge_loop<FO, false>(cols, nullptr, vcsr, HP, rptr[2 * N_ + r], rptr[2 * N_ + r + 1], lane,
                             0.f, 2 * NNZ_, ax, ay, az, aw, z);
        ox += ax; oy += ay; oz += az; ow += aw;
    }
    ox = fmaxf(ox, 0.f); oy = fmaxf(oy, 0.f);
    oz = fmaxf(oz, 0.f); ow = fmaxf(ow, 0.f);
    *reinterpret_cast<float4*>(xout + (size_t)r * FO + lane * 4) = make_float4(ox, oy, oz, ow);
}

// ---------------- pooling + softmax ----------------

__global__ __launch_bounds__(256) void pool_k(const float* __restrict__ x, const int* __restrict__ batch,
                                              float* __restrict__ out) {
    int g = blockIdx.x;
    __shared__ float part[256];
    __shared__ int sse[2];
    if (threadIdx.x < 2) {
        int target = g + threadIdx.x;
        int lo = 0, hi = N_;
        while (lo < hi) {
            int mid = (lo + hi) >> 1;
            if (batch[mid] < target) lo = mid + 1; else hi = mid;
        }
        sse[threadIdx.x] = lo;
    }
    __syncthreads();
    int s = sse[0], e = sse[1];
    int f = threadIdx.x % 8;
    float acc = 0.f;
    for (int i = s + threadIdx.x / 8; i < e; i += 32) acc += fabsf(x[(size_t)i * 8 + f]);
    part[threadIdx.x] = acc;
    __syncthreads();
    if (threadIdx.x < 8) {
        float t = 0.f;
        #pragma unroll
        for (int k = 0; k < 32; ++k) t += part[k * 8 + f];
        float cnt = (float)(e - s);
        part[f] = t / fmaxf(cnt, 1.0f);
    }
    __syncthreads();
    if (threadIdx.x == 0) {
        float m = part[0];
        for (int j = 1; j < 8; ++j) m = fmaxf(m, part[j]);
        float zs = 0.f;
        float ex[8];
        for (int j = 0; j < 8; ++j) { ex[j] = __expf(part[j] - m); zs += ex[j]; }
        for (int j = 0; j < 8; ++j) out[g * 8 + j] = ex[j] / zs;
    }
}

// ---------------- layer driver ----------------

template <int FI, int FO>
static void run_layer(const float* xin, float* xout, const float* const* W,
                      float* HU, float* HD, float* HP,
                      float* SSU, float* SDU, float* SSD, float* SDD,
                      const int* PTR, const int* COLS, const float* VCSR, hipStream_t stream) {
    // W = {pW, uW, uas, uad, dW, das, dad}
    constexpr int ROWS = 256 / FO;
    constexpr int RPB = 256 / (FO / 4);
    gemm3_k<FI, FO><<<(N_ + ROWS - 1) / ROWS, 256, 0, stream>>>(
        xin, W[1], W[2], W[3], W[4], W[5], W[6], W[0],
        HU, HD, HP, SSU, SDU, SSD, SDD);
    gather3_k<FO><<<(N_ + RPB - 1) / RPB, 256, 0, stream>>>(
        PTR, COLS, VCSR, HU, HD, HP, SSU, SDU, SSD, SDD, xout);
}

extern "C" void kernel_launch(void* const* d_in, const int* in_sizes, int n_in, void* d_out,
                              int out_size, void* d_ws, size_t ws_size, hipStream_t stream) {
    (void)in_sizes; (void)n_in; (void)out_size; (void)ws_size;
    const float* x1     = (const float*)d_in[0];
    const int*   l1_idx = (const int*)d_in[29];
    const float* l1_val = (const float*)d_in[30];
    const int*   lu_idx = (const int*)d_in[31];
    const int*   ld_idx = (const int*)d_in[32];
    const int*   batch1 = (const int*)d_in[33];
    float* out = (float*)d_out;

    char* w = (char*)d_ws;
    size_t off = 0;
    auto alloc = [&](size_t bytes) -> char* {
        char* p = w + off;
        off = (off + bytes + 255) & ~(size_t)255;
        return p;
    };
    float* X    = (float*)alloc((size_t)N_ * 32 * 4);   // in-place layer state
    float* HU   = (float*)alloc((size_t)N_ * 32 * 4);
    float* HD   = (float*)alloc((size_t)N_ * 32 * 4);
    float* HP   = (float*)alloc((size_t)N_ * 32 * 4);
    float* SSU  = (float*)alloc((size_t)N_ * 4);
    float* SDU  = (float*)alloc((size_t)N_ * 4);
    float* SSD  = (float*)alloc((size_t)N_ * 4);
    float* SDD  = (float*)alloc((size_t)N_ * 4);
    int*   PTR  = (int*)alloc((size_t)(3 * N_ + 1) * 4);
    int*   DEG  = (int*)alloc((size_t)3 * N_ * 4);
    int*   BSUM = (int*)alloc((size_t)1024 * 4);
    int*   TICK = (int*)alloc((size_t)3 * NNZ_ * 4);
    int*   COLS = (int*)alloc((size_t)3 * NNZ_ * 4);
    float* VCSR = (float*)alloc((size_t)NNZ_ * 4);

    // ---- CSR build (indices layer-invariant: build once, reuse 4x) ----
    hipMemsetAsync(DEG, 0, (size_t)3 * N_ * 4, stream);
    int qbl = (NNZ_ / 4 + 255) / 256;
    hist_k<<<qbl, 256, 0, stream>>>(lu_idx, ld_idx, l1_idx, DEG, TICK);
    int n3 = 3 * N_;
    int nb = (n3 + 1023) / 1024;
    scan1_k<<<nb, 256, 0, stream>>>(DEG, PTR, BSUM, n3);
    scan2_k<<<1, 256, 0, stream>>>(BSUM, nb, PTR + n3);
    scan3_k<<<nb, 256, 0, stream>>>(PTR, BSUM, n3);
    scatter_k<<<qbl, 256, 0, stream>>>(lu_idx, ld_idx, l1_idx, l1_val, PTR, TICK, COLS, VCSR);

    // ---- 4 SAN layers (fused per layer) ----
    const float* W0[7] = {(const float*)d_in[1], (const float*)d_in[2], (const float*)d_in[3],
                          (const float*)d_in[4], (const float*)d_in[5], (const float*)d_in[6],
                          (const float*)d_in[7]};
    const float* W1[7] = {(const float*)d_in[8],  (const float*)d_in[9],  (const float*)d_in[10],
                          (const float*)d_in[11], (const float*)d_in[12], (const float*)d_in[13],
                          (const float*)d_in[14]};
    const float* W2[7] = {(const float*)d_in[15], (const float*)d_in[16], (const float*)d_in[17],
                          (const float*)d_in[18], (const float*)d_in[19], (const float*)d_in[20],
                          (const float*)d_in[21]};
    const float* W3[7] = {(const float*)d_in[22], (const float*)d_in[23], (const float*)d_in[24],
                          (const float*)d_in[25], (const float*)d_in[26], (const float*)d_in[27],
                          (const float*)d_in[28]};

    run_layer<64, 32>(x1, X, W0, HU, HD, HP, SSU, SDU, SSD, SDD, PTR, COLS, VCSR, stream);
    run_layer<32, 32>(X, X, W1, HU, HD, HP, SSU, SDU, SSD, SDD, PTR, COLS, VCSR, stream);
    run_layer<32, 32>(X, X, W2, HU, HD, HP, SSU, SDU, SSD, SDD, PTR, COLS, VCSR, stream);
    run_layer<32, 8>(X, X, W3, HU, HD, HP, SSU, SDU, SSD, SDD, PTR, COLS, VCSR, stream);

    // ---- global mean pool of |x| + row softmax ----
    pool_k<<<G_, 256, 0, stream>>>(X, batch1, out);
}

// Round 5
// 1544.122 us; speedup vs baseline: 1.2032x; 1.0052x over previous
//
#include <hip/hip_runtime.h>
#include <cmath>

// Round 5: (1) gather3_k: 2-team row split (2x outstanding misses, half the
// serial chain) + predicated 4-wide tail (no serial scalar tail).
// (2) scatter fused with layer-1 gemm3 (independent work, grid-partitioned;
// GEMM hides under latency-bound scatter); scatter loads hand-hoisted.

#define N_    200000
#define NNZ_  2000000
#define G_    256

// ---------------- CSR build ----------------

__global__ __launch_bounds__(256) void hist_k(const int* __restrict__ lu, const int* __restrict__ ld,
                                              const int* __restrict__ l1, int* __restrict__ deg,
                                              int* __restrict__ tick) {
    int i = blockIdx.x * 256 + threadIdx.x;
    if (i >= NNZ_ / 4) return;
    int e = i * 4;
    int4 ru = *reinterpret_cast<const int4*>(lu + e);
    int4 rd = *reinterpret_cast<const int4*>(ld + e);
    int4 rl = *reinterpret_cast<const int4*>(l1 + e);
    int4 t;
    t.x = atomicAdd(&deg[ru.x], 1);
    t.y = atomicAdd(&deg[ru.y], 1);
    t.z = atomicAdd(&deg[ru.z], 1);
    t.w = atomicAdd(&deg[ru.w], 1);
    *reinterpret_cast<int4*>(tick + e) = t;
    t.x = atomicAdd(&deg[N_ + rd.x], 1);
    t.y = atomicAdd(&deg[N_ + rd.y], 1);
    t.z = atomicAdd(&deg[N_ + rd.z], 1);
    t.w = atomicAdd(&deg[N_ + rd.w], 1);
    *reinterpret_cast<int4*>(tick + NNZ_ + e) = t;
    t.x = atomicAdd(&deg[2 * N_ + rl.x], 1);
    t.y = atomicAdd(&deg[2 * N_ + rl.y], 1);
    t.z = atomicAdd(&deg[2 * N_ + rl.z], 1);
    t.w = atomicAdd(&deg[2 * N_ + rl.w], 1);
    *reinterpret_cast<int4*>(tick + 2 * NNZ_ + e) = t;
}

__global__ __launch_bounds__(256) void scan1_k(const int* __restrict__ in, int* __restrict__ out,
                                               int* __restrict__ bsum, int n) {
    __shared__ int lds[256];
    int tid = threadIdx.x;
    int base = blockIdx.x * 1024 + tid * 4;
    int v0 = (base + 0 < n) ? in[base + 0] : 0;
    int v1 = (base + 1 < n) ? in[base + 1] : 0;
    int v2 = (base + 2 < n) ? in[base + 2] : 0;
    int v3 = (base + 3 < n) ? in[base + 3] : 0;
    int s = v0 + v1 + v2 + v3;
    lds[tid] = s;
    __syncthreads();
    for (int off = 1; off < 256; off <<= 1) {
        int t = (tid >= off) ? lds[tid - off] : 0;
        __syncthreads();
        lds[tid] += t;
        __syncthreads();
    }
    int excl = lds[tid] - s;
    if (base + 0 < n) out[base + 0] = excl;
    if (base + 1 < n) out[base + 1] = excl + v0;
    if (base + 2 < n) out[base + 2] = excl + v0 + v1;
    if (base + 3 < n) out[base + 3] = excl + v0 + v1 + v2;
    if (tid == 255) bsum[blockIdx.x] = lds[255];
}

__global__ __launch_bounds__(256) void scan2_k(int* __restrict__ bsum, int nb, int* __restrict__ total_out) {
    __shared__ int lds[256];
    __shared__ int run_s;
    int tid = threadIdx.x;
    if (tid == 0) run_s = 0;
    __syncthreads();
    for (int c0 = 0; c0 < nb; c0 += 256) {
        int i = c0 + tid;
        int s = (i < nb) ? bsum[i] : 0;
        lds[tid] = s;
        __syncthreads();
        for (int off = 1; off < 256; off <<= 1) {
            int t = (tid >= off) ? lds[tid - off] : 0;
            __syncthreads();
            lds[tid] += t;
            __syncthreads();
        }
        int run = run_s;
        if (i < nb) bsum[i] = run + lds[tid] - s;
        __syncthreads();
        if (tid == 0) run_s = run + lds[255];
        __syncthreads();
    }
    if (tid == 0 && total_out) *total_out = run_s;
}

__global__ __launch_bounds__(256) void scan3_k(int* __restrict__ out, const int* __restrict__ bsum, int n) {
    int add = bsum[blockIdx.x];
    int base = blockIdx.x * 1024 + threadIdx.x * 4;
    #pragma unroll
    for (int k = 0; k < 4; ++k)
        if (base + k < n) out[base + k] += add;
}

// ---- fused scatter + layer-1 gemm3 (independent work, block-partitioned) ----

template <int FI, int FO, int SCB>
__global__ __launch_bounds__(256) void scat_gemm_k(
    const int* __restrict__ lu, const int* __restrict__ ld, const int* __restrict__ l1,
    const float* __restrict__ l1v, const int* __restrict__ rptr, const int* __restrict__ tick,
    int* __restrict__ cols, float* __restrict__ vcsr,
    const float* __restrict__ x,
    const float* __restrict__ uW, const float* __restrict__ uas, const float* __restrict__ uad,
    const float* __restrict__ dW, const float* __restrict__ das, const float* __restrict__ dad,
    const float* __restrict__ pW,
    float* __restrict__ HU, float* __restrict__ HD, float* __restrict__ HP,
    float* __restrict__ ssu, float* __restrict__ sdu,
    float* __restrict__ ssd, float* __restrict__ sdd) {
    if (blockIdx.x < SCB) {
        // ---------- scatter path ----------
        int i = blockIdx.x * 256 + threadIdx.x;
        if (i >= NNZ_ / 4) return;
        int e = i * 4;
        // hoist ALL loads before stores for max memory-level parallelism
        int4 ru = *reinterpret_cast<const int4*>(lu + e);
        int4 rd = *reinterpret_cast<const int4*>(ld + e);
        int4 rl = *reinterpret_cast<const int4*>(l1 + e);
        int4 cu = *reinterpret_cast<const int4*>(lu + NNZ_ + e);
        int4 cd = *reinterpret_cast<const int4*>(ld + NNZ_ + e);
        int4 cl = *reinterpret_cast<const int4*>(l1 + NNZ_ + e);
        int4 tu = *reinterpret_cast<const int4*>(tick + e);
        int4 td = *reinterpret_cast<const int4*>(tick + NNZ_ + e);
        int4 tl = *reinterpret_cast<const int4*>(tick + 2 * NNZ_ + e);
        float4 v = *reinterpret_cast<const float4*>(l1v + e);
        int pu0 = rptr[ru.x] + tu.x, pu1 = rptr[ru.y] + tu.y;
        int pu2 = rptr[ru.z] + tu.z, pu3 = rptr[ru.w] + tu.w;
        int pd0 = rptr[N_ + rd.x] + td.x, pd1 = rptr[N_ + rd.y] + td.y;
        int pd2 = rptr[N_ + rd.z] + td.z, pd3 = rptr[N_ + rd.w] + td.w;
        int pl0 = rptr[2 * N_ + rl.x] + tl.x, pl1 = rptr[2 * N_ + rl.y] + tl.y;
        int pl2 = rptr[2 * N_ + rl.z] + tl.z, pl3 = rptr[2 * N_ + rl.w] + tl.w;
        __builtin_nontemporal_store(cu.x, &cols[pu0]);
        __builtin_nontemporal_store(cu.y, &cols[pu1]);
        __builtin_nontemporal_store(cu.z, &cols[pu2]);
        __builtin_nontemporal_store(cu.w, &cols[pu3]);
        __builtin_nontemporal_store(cd.x, &cols[pd0]);
        __builtin_nontemporal_store(cd.y, &cols[pd1]);
        __builtin_nontemporal_store(cd.z, &cols[pd2]);
        __builtin_nontemporal_store(cd.w, &cols[pd3]);
        __builtin_nontemporal_store(cl.x, &cols[pl0]);
        __builtin_nontemporal_store(cl.y, &cols[pl1]);
        __builtin_nontemporal_store(cl.z, &cols[pl2]);
        __builtin_nontemporal_store(cl.w, &cols[pl3]);
        __builtin_nontemporal_store(v.x, &vcsr[pl0 - 2 * NNZ_]);
        __builtin_nontemporal_store(v.y, &vcsr[pl1 - 2 * NNZ_]);
        __builtin_nontemporal_store(v.z, &vcsr[pl2 - 2 * NNZ_]);
        __builtin_nontemporal_store(v.w, &vcsr[pl3 - 2 * NNZ_]);
        return;
    }
    // ---------- gemm path ----------
    int bid = blockIdx.x - SCB;
    constexpr int ROWS = 256 / FO;
    constexpr int XS = FI + 1;
    __shared__ float Wu[FI * FO], Wd[FI * FO], Wp[FI * FO];
    __shared__ float xs[ROWS * XS];
    int tid = threadIdx.x;
    for (int i = tid; i < FI * FO; i += 256) {
        Wu[i] = uW[i];
        Wd[i] = dW[i];
        Wp[i] = pW[i];
    }
    int row0 = bid * ROWS;
    for (int i = tid; i < ROWS * FI; i += 256) {
        int r = i / FI, k = i - r * FI;
        int gr = row0 + r;
        xs[r * XS + k] = (gr < N_) ? x[(size_t)gr * FI + k] : 0.f;
    }
    __syncthreads();
    int r = tid / FO, j = tid - (tid / FO) * FO;
    int grow = row0 + r;
    float au = 0.f, ad = 0.f, ap = 0.f;
    #pragma unroll
    for (int k = 0; k < FI; ++k) {
        float xv = xs[r * XS + k];
        au = fmaf(xv, Wu[k * FO + j], au);
        ad = fmaf(xv, Wd[k * FO + j], ad);
        ap = fmaf(xv, Wp[k * FO + j], ap);
    }
    if (grow < N_) {
        HU[(size_t)grow * FO + j] = au;
        HD[(size_t)grow * FO + j] = ad;
        HP[(size_t)grow * FO + j] = ap;
    }
    float vsu = au * uas[j], vdu = au * uad[j];
    float vsd = ad * das[j], vdd = ad * dad[j];
    #pragma unroll
    for (int m = FO / 2; m >= 1; m >>= 1) {
        vsu += __shfl_xor(vsu, m, FO);
        vdu += __shfl_xor(vdu, m, FO);
        vsd += __shfl_xor(vsd, m, FO);
        vdd += __shfl_xor(vdd, m, FO);
    }
    if (j == 0 && grow < N_) {
        ssu[grow] = vsu; sdu[grow] = vdu;
        ssd[grow] = vsd; sdd[grow] = vdd;
    }
}

// ---------------- fused dense (standalone, layers 2-4) ----------------

template <int FI, int FO>
__global__ __launch_bounds__(256) void gemm3_k(const float* __restrict__ x,
                                               const float* __restrict__ uW, const float* __restrict__ uas,
                                               const float* __restrict__ uad,
                                               const float* __restrict__ dW, const float* __restrict__ das,
                                               const float* __restrict__ dad,
                                               const float* __restrict__ pW,
                                               float* __restrict__ HU, float* __restrict__ HD,
                                               float* __restrict__ HP,
                                               float* __restrict__ ssu, float* __restrict__ sdu,
                                               float* __restrict__ ssd, float* __restrict__ sdd) {
    constexpr int ROWS = 256 / FO;
    constexpr int XS = FI + 1;
    __shared__ float Wu[FI * FO], Wd[FI * FO], Wp[FI * FO];
    __shared__ float xs[ROWS * XS];
    int tid = threadIdx.x;
    for (int i = tid; i < FI * FO; i += 256) {
        Wu[i] = uW[i];
        Wd[i] = dW[i];
        Wp[i] = pW[i];
    }
    int row0 = blockIdx.x * ROWS;
    for (int i = tid; i < ROWS * FI; i += 256) {
        int r = i / FI, k = i - r * FI;
        int gr = row0 + r;
        xs[r * XS + k] = (gr < N_) ? x[(size_t)gr * FI + k] : 0.f;
    }
    __syncthreads();
    int r = tid / FO, j = tid - (tid / FO) * FO;
    int grow = row0 + r;
    float au = 0.f, ad = 0.f, ap = 0.f;
    #pragma unroll
    for (int k = 0; k < FI; ++k) {
        float xv = xs[r * XS + k];
        au = fmaf(xv, Wu[k * FO + j], au);
        ad = fmaf(xv, Wd[k * FO + j], ad);
        ap = fmaf(xv, Wp[k * FO + j], ap);
    }
    if (grow < N_) {
        HU[(size_t)grow * FO + j] = au;
        HD[(size_t)grow * FO + j] = ad;
        HP[(size_t)grow * FO + j] = ap;
    }
    float vsu = au * uas[j], vdu = au * uad[j];
    float vsd = ad * das[j], vdd = ad * dad[j];
    #pragma unroll
    for (int m = FO / 2; m >= 1; m >>= 1) {
        vsu += __shfl_xor(vsu, m, FO);
        vdu += __shfl_xor(vdu, m, FO);
        vsd += __shfl_xor(vsd, m, FO);
        vdd += __shfl_xor(vdd, m, FO);
    }
    if (j == 0 && grow < N_) {
        ssu[grow] = vsu; sdu[grow] = vdu;
        ssd[grow] = vsd; sdd[grow] = vdd;
    }
}

// ---------------- fused sparse gather (u + d + p, team-split rows) --------

template <int FO, bool GAT>
__device__ __forceinline__ void edge_loop(const int* __restrict__ cols, const float* __restrict__ sdv,
                                          const float* __restrict__ vals, const float* __restrict__ H,
                                          int b, int e, int lane, float s_row, int vbase,
                                          float& ax, float& ay, float& az, float& aw, float& z) {
    // predicated 4-wide loop: indices clamped to e-1 (valid since b<e),
    // weights zeroed for out-of-range slots -> always 4 gathers in flight.
    for (int p = b; p < e; p += 4) {
        int q1 = p + 1 < e ? p + 1 : e - 1;
        int q2 = p + 2 < e ? p + 2 : e - 1;
        int q3 = p + 3 < e ? p + 3 : e - 1;
        int c0 = cols[p], c1 = cols[q1], c2 = cols[q2], c3 = cols[q3];
        const float4 h0 = *reinterpret_cast<const float4*>(H + (size_t)c0 * FO + lane * 4);
        const float4 h1 = *reinterpret_cast<const float4*>(H + (size_t)c1 * FO + lane * 4);
        const float4 h2 = *reinterpret_cast<const float4*>(H + (size_t)c2 * FO + lane * 4);
        const float4 h3 = *reinterpret_cast<const float4*>(H + (size_t)c3 * FO + lane * 4);
        float w0, w1, w2, w3;
        if constexpr (GAT) {
            float g0 = s_row + sdv[c0];
            float g1 = s_row + sdv[c1];
            float g2 = s_row + sdv[c2];
            float g3 = s_row + sdv[c3];
            g0 = g0 > 0.f ? g0 : 0.2f * g0;
            g1 = g1 > 0.f ? g1 : 0.2f * g1;
            g2 = g2 > 0.f ? g2 : 0.2f * g2;
            g3 = g3 > 0.f ? g3 : 0.2f * g3;
            w0 = __expf(g0);
            w1 = p + 1 < e ? __expf(g1) : 0.f;
            w2 = p + 2 < e ? __expf(g2) : 0.f;
            w3 = p + 3 < e ? __expf(g3) : 0.f;
            z += (w0 + w1) + (w2 + w3);
        } else {
            w0 = vals[p - vbase];
            w1 = p + 1 < e ? vals[q1 - vbase] : 0.f;
            w2 = p + 2 < e ? vals[q2 - vbase] : 0.f;
            w3 = p + 3 < e ? vals[q3 - vbase] : 0.f;
        }
        ax = fmaf(w0, h0.x, ax); ay = fmaf(w0, h0.y, ay);
        az = fmaf(w0, h0.z, az); aw = fmaf(w0, h0.w, aw);
        ax = fmaf(w1, h1.x, ax); ay = fmaf(w1, h1.y, ay);
        az = fmaf(w1, h1.z, az); aw = fmaf(w1, h1.w, aw);
        ax = fmaf(w2, h2.x, ax); ay = fmaf(w2, h2.y, ay);
        az = fmaf(w2, h2.z, az); aw = fmaf(w2, h2.w, aw);
        ax = fmaf(w3, h3.x, ax); ay = fmaf(w3, h3.y, ay);
        az = fmaf(w3, h3.z, az); aw = fmaf(w3, h3.w, aw);
    }
}

template <int FO, int TEAMS>
__global__ __launch_bounds__(256) void gather3_k(const int* __restrict__ rptr, const int* __restrict__ cols,
                                                 const float* __restrict__ vcsr,
                                                 const float* __restrict__ HU, const float* __restrict__ HD,
                                                 const float* __restrict__ HP,
                                                 const float* __restrict__ ssu, const float* __restrict__ sdu,
                                                 const float* __restrict__ ssd, const float* __restrict__ sdd,
                                                 float* __restrict__ xout) {
    constexpr int LPR = FO / 4;          // lanes per row (16B slices)
    constexpr int TPR = LPR * TEAMS;     // threads per row
    constexpr int RPB = 256 / TPR;       // rows per block
    int tid = threadIdx.x;
    int lane = tid & (LPR - 1);
    int team = (tid / LPR) & (TEAMS - 1);
    int r = blockIdx.x * RPB + tid / TPR;
    if (r >= N_) return;
    float ox = 0.f, oy = 0.f, oz = 0.f, ow = 0.f;

    auto branch = [&](const float* H, const float* sdv, const float* vals, int base, int vbase,
                      bool gat, float s_row, float& bx, float& by, float& bz, float& bw, float& z) {
        int b0 = rptr[base + r], e0 = rptr[base + r + 1];
        int half = (e0 - b0) >> 1;
        int tb = team == 0 ? b0 : b0 + half;
        int te = team == 0 ? b0 + half : e0;
        if (tb < te) {
            if (gat)
                edge_loop<FO, true>(cols, sdv, nullptr, H, tb, te, lane, s_row, 0, bx, by, bz, bw, z);
            else
                edge_loop<FO, false>(cols, nullptr, vals, H, tb, te, lane, 0.f, vbase, bx, by, bz, bw, z);
        }
        // combine the two teams (partners share the same row)
        bx += __shfl_xor(bx, LPR, TPR);
        by += __shfl_xor(by, LPR, TPR);
        bz += __shfl_xor(bz, LPR, TPR);
        bw += __shfl_xor(bw, LPR, TPR);
        if (gat) z += __shfl_xor(z, LPR, TPR);
    };

    {   // u branch
        float ax = 0.f, ay = 0.f, az = 0.f, aw = 0.f, z = 0.f;
        branch(HU, sdu, nullptr, 0, 0, true, ssu[r], ax, ay, az, aw, z);
        float inv = 1.f / (z + 1e-16f);
        ox = ax * inv; oy = ay * inv; oz = az * inv; ow = aw * inv;
    }
    {   // d branch
        float ax = 0.f, ay = 0.f, az = 0.f, aw = 0.f, z = 0.f;
        branch(HD, sdd, nullptr, N_, 0, true, ssd[r], ax, ay, az, aw, z);
        float inv = 1.f / (z + 1e-16f);
        ox = fmaf(ax, inv, ox); oy = fmaf(ay, inv, oy);
        oz = fmaf(az, inv, oz); ow = fmaf(aw, inv, ow);
    }
    {   // p branch
        float ax = 0.f, ay = 0.f, az = 0.f, aw = 0.f, z = 0.f;
        branch(HP, nullptr, vcsr, 2 * N_, 2 * NNZ_, false, 0.f, ax, ay, az, aw, z);
        ox += ax; oy += ay; oz += az; ow += aw;
    }
    if (team == 0) {
        ox = fmaxf(ox, 0.f); oy = fmaxf(oy, 0.f);
        oz = fmaxf(oz, 0.f); ow = fmaxf(ow, 0.f);
        *reinterpret_cast<float4*>(xout + (size_t)r * FO + lane * 4) = make_float4(ox, oy, oz, ow);
    }
}

// ---------------- pooling + softmax ----------------

__global__ __launch_bounds__(256) void pool_k(const float* __restrict__ x, const int* __restrict__ batch,
                                              float* __restrict__ out) {
    int g = blockIdx.x;
    __shared__ float part[256];
    __shared__ int sse[2];
    if (threadIdx.x < 2) {
        int target = g + threadIdx.x;
        int lo = 0, hi = N_;
        while (lo < hi) {
            int mid = (lo + hi) >> 1;
            if (batch[mid] < target) lo = mid + 1; else hi = mid;
        }
        sse[threadIdx.x] = lo;
    }
    __syncthreads();
    int s = sse[0], e = sse[1];
    int f = threadIdx.x % 8;
    float acc = 0.f;
    for (int i = s + threadIdx.x / 8; i < e; i += 32) acc += fabsf(x[(size_t)i * 8 + f]);
    part[threadIdx.x] = acc;
    __syncthreads();
    if (threadIdx.x < 8) {
        float t = 0.f;
        #pragma unroll
        for (int k = 0; k < 32; ++k) t += part[k * 8 + f];
        float cnt = (float)(e - s);
        part[f] = t / fmaxf(cnt, 1.0f);
    }
    __syncthreads();
    if (threadIdx.x == 0) {
        float m = part[0];
        for (int j = 1; j < 8; ++j) m = fmaxf(m, part[j]);
        float zs = 0.f;
        float ex[8];
        for (int j = 0; j < 8; ++j) { ex[j] = __expf(part[j] - m); zs += ex[j]; }
        for (int j = 0; j < 8; ++j) out[g * 8 + j] = ex[j] / zs;
    }
}

// ---------------- drivers ----------------

template <int FI, int FO>
static void run_layer(const float* xin, float* xout, const float* const* W,
                      float* HU, float* HD, float* HP,
                      float* SSU, float* SDU, float* SSD, float* SDD,
                      const int* PTR, const int* COLS, const float* VCSR, hipStream_t stream) {
    // W = {pW, uW, uas, uad, dW, das, dad}
    constexpr int ROWS = 256 / FO;
    constexpr int RPB = 256 / ((FO / 4) * 2);
    gemm3_k<FI, FO><<<(N_ + ROWS - 1) / ROWS, 256, 0, stream>>>(
        xin, W[1], W[2], W[3], W[4], W[5], W[6], W[0],
        HU, HD, HP, SSU, SDU, SSD, SDD);
    gather3_k<FO, 2><<<(N_ + RPB - 1) / RPB, 256, 0, stream>>>(
        PTR, COLS, VCSR, HU, HD, HP, SSU, SDU, SSD, SDD, xout);
}

extern "C" void kernel_launch(void* const* d_in, const int* in_sizes, int n_in, void* d_out,
                              int out_size, void* d_ws, size_t ws_size, hipStream_t stream) {
    (void)in_sizes; (void)n_in; (void)out_size; (void)ws_size;
    const float* x1     = (const float*)d_in[0];
    const int*   l1_idx = (const int*)d_in[29];
    const float* l1_val = (const float*)d_in[30];
    const int*   lu_idx = (const int*)d_in[31];
    const int*   ld_idx = (const int*)d_in[32];
    const int*   batch1 = (const int*)d_in[33];
    float* out = (float*)d_out;

    char* w = (char*)d_ws;
    size_t off = 0;
    auto alloc = [&](size_t bytes) -> char* {
        char* p = w + off;
        off = (off + bytes + 255) & ~(size_t)255;
        return p;
    };
    float* X    = (float*)alloc((size_t)N_ * 32 * 4);   // in-place layer state
    float* HU   = (float*)alloc((size_t)N_ * 32 * 4);
    float* HD   = (float*)alloc((size_t)N_ * 32 * 4);
    float* HP   = (float*)alloc((size_t)N_ * 32 * 4);
    float* SSU  = (float*)alloc((size_t)N_ * 4);
    float* SDU  = (float*)alloc((size_t)N_ * 4);
    float* SSD  = (float*)alloc((size_t)N_ * 4);
    float* SDD  = (float*)alloc((size_t)N_ * 4);
    int*   PTR  = (int*)alloc((size_t)(3 * N_ + 1) * 4);
    int*   DEG  = (int*)alloc((size_t)3 * N_ * 4);
    int*   BSUM = (int*)alloc((size_t)1024 * 4);
    int*   TICK = (int*)alloc((size_t)3 * NNZ_ * 4);
    int*   COLS = (int*)alloc((size_t)3 * NNZ_ * 4);
    float* VCSR = (float*)alloc((size_t)NNZ_ * 4);

    const float* W0[7] = {(const float*)d_in[1], (const float*)d_in[2], (const float*)d_in[3],
                          (const float*)d_in[4], (const float*)d_in[5], (const float*)d_in[6],
                          (const float*)d_in[7]};
    const float* W1[7] = {(const float*)d_in[8],  (const float*)d_in[9],  (const float*)d_in[10],
                          (const float*)d_in[11], (const float*)d_in[12], (const float*)d_in[13],
                          (const float*)d_in[14]};
    const float* W2[7] = {(const float*)d_in[15], (const float*)d_in[16], (const float*)d_in[17],
                          (const float*)d_in[18], (const float*)d_in[19], (const float*)d_in[20],
                          (const float*)d_in[21]};
    const float* W3[7] = {(const float*)d_in[22], (const float*)d_in[23], (const float*)d_in[24],
                          (const float*)d_in[25], (const float*)d_in[26], (const float*)d_in[27],
                          (const float*)d_in[28]};

    // ---- CSR build (layer-invariant; reused 4x) ----
    hipMemsetAsync(DEG, 0, (size_t)3 * N_ * 4, stream);
    constexpr int QBL = (NNZ_ / 4 + 255) / 256;
    hist_k<<<QBL, 256, 0, stream>>>(lu_idx, ld_idx, l1_idx, DEG, TICK);
    int n3 = 3 * N_;
    int nb = (n3 + 1023) / 1024;
    scan1_k<<<nb, 256, 0, stream>>>(DEG, PTR, BSUM, n3);
    scan2_k<<<1, 256, 0, stream>>>(BSUM, nb, PTR + n3);
    scan3_k<<<nb, 256, 0, stream>>>(PTR, BSUM, n3);

    // ---- scatter fused with layer-1 GEMM (independent; GEMM hides under scatter) ----
    {
        constexpr int ROWS = 256 / 32;
        int gemmb = (N_ + ROWS - 1) / ROWS;
        scat_gemm_k<64, 32, QBL><<<QBL + gemmb, 256, 0, stream>>>(
            lu_idx, ld_idx, l1_idx, l1_val, PTR, TICK, COLS, VCSR,
            x1, W0[1], W0[2], W0[3], W0[4], W0[5], W0[6], W0[0],
            HU, HD, HP, SSU, SDU, SSD, SDD);
    }
    {
        constexpr int RPB = 256 / ((32 / 4) * 2);
        gather3_k<32, 2><<<(N_ + RPB - 1) / RPB, 256, 0, stream>>>(
            PTR, COLS, VCSR, HU, HD, HP, SSU, SDU, SSD, SDD, X);
    }

    // ---- layers 2-4 ----
    run_layer<32, 32>(X, X, W1, HU, HD, HP, SSU, SDU, SSD, SDD, PTR, COLS, VCSR, stream);
    run_layer<32, 32>(X, X, W2, HU, HD, HP, SSU, SDU, SSD, SDD, PTR, COLS, VCSR, stream);
    run_layer<32, 8>(X, X, W3, HU, HD, HP, SSU, SDU, SSD, SDD, PTR, COLS, VCSR, stream);

    // ---- global mean pool of |x| + row softmax ----
    pool_k<<<G_, 256, 0, stream>>>(X, batch1, out);
}

// Round 8
// 1474.245 us; speedup vs baseline: 1.2602x; 1.0474x over previous
//
#include <hip/hip_runtime.h>
#include <hip/hip_fp16.h>
#include <cmath>

// Round 8: identical to round 7 (round-7 bench failed on GPU acquisition
// timeout, not on the kernel). Round-6 structure + OOB rebase fix in
// gather3_k; see round-7 analysis.

#define N_    200000
#define NNZ_  2000000
#define G_    256

// ---------------- CSR build ----------------

__global__ __launch_bounds__(256) void hist_k(const int* __restrict__ lu, const int* __restrict__ ld,
                                              const int* __restrict__ l1, int* __restrict__ deg,
                                              int* __restrict__ tick) {
    int i = blockIdx.x * 256 + threadIdx.x;
    if (i >= NNZ_ / 4) return;
    int e = i * 4;
    int4 ru = *reinterpret_cast<const int4*>(lu + e);
    int4 rd = *reinterpret_cast<const int4*>(ld + e);
    int4 rl = *reinterpret_cast<const int4*>(l1 + e);
    int4 t;
    t.x = atomicAdd(&deg[ru.x], 1);
    t.y = atomicAdd(&deg[ru.y], 1);
    t.z = atomicAdd(&deg[ru.z], 1);
    t.w = atomicAdd(&deg[ru.w], 1);
    *reinterpret_cast<int4*>(tick + e) = t;
    t.x = atomicAdd(&deg[N_ + rd.x], 1);
    t.y = atomicAdd(&deg[N_ + rd.y], 1);
    t.z = atomicAdd(&deg[N_ + rd.z], 1);
    t.w = atomicAdd(&deg[N_ + rd.w], 1);
    *reinterpret_cast<int4*>(tick + NNZ_ + e) = t;
    t.x = atomicAdd(&deg[2 * N_ + rl.x], 1);
    t.y = atomicAdd(&deg[2 * N_ + rl.y], 1);
    t.z = atomicAdd(&deg[2 * N_ + rl.z], 1);
    t.w = atomicAdd(&deg[2 * N_ + rl.w], 1);
    *reinterpret_cast<int4*>(tick + 2 * NNZ_ + e) = t;
}

__global__ __launch_bounds__(256) void scan1_k(const int* __restrict__ in, int* __restrict__ out,
                                               int* __restrict__ bsum, int n) {
    __shared__ int lds[256];
    int tid = threadIdx.x;
    int base = blockIdx.x * 1024 + tid * 4;
    int v0 = (base + 0 < n) ? in[base + 0] : 0;
    int v1 = (base + 1 < n) ? in[base + 1] : 0;
    int v2 = (base + 2 < n) ? in[base + 2] : 0;
    int v3 = (base + 3 < n) ? in[base + 3] : 0;
    int s = v0 + v1 + v2 + v3;
    lds[tid] = s;
    __syncthreads();
    for (int off = 1; off < 256; off <<= 1) {
        int t = (tid >= off) ? lds[tid - off] : 0;
        __syncthreads();
        lds[tid] += t;
        __syncthreads();
    }
    int excl = lds[tid] - s;
    if (base + 0 < n) out[base + 0] = excl;
    if (base + 1 < n) out[base + 1] = excl + v0;
    if (base + 2 < n) out[base + 2] = excl + v0 + v1;
    if (base + 3 < n) out[base + 3] = excl + v0 + v1 + v2;
    if (tid == 255) bsum[blockIdx.x] = lds[255];
}

__global__ __launch_bounds__(256) void scan2_k(int* __restrict__ bsum, int nb, int* __restrict__ total_out) {
    __shared__ int lds[256];
    __shared__ int run_s;
    int tid = threadIdx.x;
    if (tid == 0) run_s = 0;
    __syncthreads();
    for (int c0 = 0; c0 < nb; c0 += 256) {
        int i = c0 + tid;
        int s = (i < nb) ? bsum[i] : 0;
        lds[tid] = s;
        __syncthreads();
        for (int off = 1; off < 256; off <<= 1) {
            int t = (tid >= off) ? lds[tid - off] : 0;
            __syncthreads();
            lds[tid] += t;
            __syncthreads();
        }
        int run = run_s;
        if (i < nb) bsum[i] = run + lds[tid] - s;
        __syncthreads();
        if (tid == 0) run_s = run + lds[255];
        __syncthreads();
    }
    if (tid == 0 && total_out) *total_out = run_s;
}

__global__ __launch_bounds__(256) void scan3_k(int* __restrict__ out, const int* __restrict__ bsum, int n) {
    int add = bsum[blockIdx.x];
    int base = blockIdx.x * 1024 + threadIdx.x * 4;
    #pragma unroll
    for (int k = 0; k < 4; ++k)
        if (base + k < n) out[base + k] += add;
}

// ---- fused scatter + layer-1 gemm3, INTERLEAVED roles (1 scatter : 12 gemm) ----

template <int FI, int FO, int SCB>
__global__ __launch_bounds__(256) void scat_gemm_k(
    const int* __restrict__ lu, const int* __restrict__ ld, const int* __restrict__ l1,
    const float* __restrict__ l1v, const int* __restrict__ rptr, const int* __restrict__ tick,
    int* __restrict__ cols_u, int* __restrict__ cols_d, int2* __restrict__ pl,
    const float* __restrict__ x,
    const float* __restrict__ uW, const float* __restrict__ uas, const float* __restrict__ uad,
    const float* __restrict__ dW, const float* __restrict__ das, const float* __restrict__ dad,
    const float* __restrict__ pW,
    __half* __restrict__ HU, __half* __restrict__ HD, __half* __restrict__ HP,
    float* __restrict__ ssu, float* __restrict__ sdu,
    float* __restrict__ ssd, float* __restrict__ sdd) {
    if (blockIdx.x % 13 == 0) {
        // ---------- scatter path ----------
        int sid = blockIdx.x / 13;
        if (sid >= SCB) return;
        int i = sid * 256 + threadIdx.x;
        if (i >= NNZ_ / 4) return;
        int e = i * 4;
        int4 ru = *reinterpret_cast<const int4*>(lu + e);
        int4 rd = *reinterpret_cast<const int4*>(ld + e);
        int4 rl = *reinterpret_cast<const int4*>(l1 + e);
        int4 cu = *reinterpret_cast<const int4*>(lu + NNZ_ + e);
        int4 cd = *reinterpret_cast<const int4*>(ld + NNZ_ + e);
        int4 cl = *reinterpret_cast<const int4*>(l1 + NNZ_ + e);
        int4 tu = *reinterpret_cast<const int4*>(tick + e);
        int4 td = *reinterpret_cast<const int4*>(tick + NNZ_ + e);
        int4 tl = *reinterpret_cast<const int4*>(tick + 2 * NNZ_ + e);
        float4 v = *reinterpret_cast<const float4*>(l1v + e);
        int pu0 = rptr[ru.x] + tu.x, pu1 = rptr[ru.y] + tu.y;
        int pu2 = rptr[ru.z] + tu.z, pu3 = rptr[ru.w] + tu.w;
        int pd0 = rptr[N_ + rd.x] + td.x - NNZ_, pd1 = rptr[N_ + rd.y] + td.y - NNZ_;
        int pd2 = rptr[N_ + rd.z] + td.z - NNZ_, pd3 = rptr[N_ + rd.w] + td.w - NNZ_;
        int pl0 = rptr[2 * N_ + rl.x] + tl.x - 2 * NNZ_, pl1 = rptr[2 * N_ + rl.y] + tl.y - 2 * NNZ_;
        int pl2 = rptr[2 * N_ + rl.z] + tl.z - 2 * NNZ_, pl3 = rptr[2 * N_ + rl.w] + tl.w - 2 * NNZ_;
        __builtin_nontemporal_store(cu.x, &cols_u[pu0]);
        __builtin_nontemporal_store(cu.y, &cols_u[pu1]);
        __builtin_nontemporal_store(cu.z, &cols_u[pu2]);
        __builtin_nontemporal_store(cu.w, &cols_u[pu3]);
        __builtin_nontemporal_store(cd.x, &cols_d[pd0]);
        __builtin_nontemporal_store(cd.y, &cols_d[pd1]);
        __builtin_nontemporal_store(cd.z, &cols_d[pd2]);
        __builtin_nontemporal_store(cd.w, &cols_d[pd3]);
        long long q0 = ((long long)__float_as_int(v.x) << 32) | (unsigned)cl.x;
        long long q1 = ((long long)__float_as_int(v.y) << 32) | (unsigned)cl.y;
        long long q2 = ((long long)__float_as_int(v.z) << 32) | (unsigned)cl.z;
        long long q3 = ((long long)__float_as_int(v.w) << 32) | (unsigned)cl.w;
        __builtin_nontemporal_store(q0, (long long*)&pl[pl0]);
        __builtin_nontemporal_store(q1, (long long*)&pl[pl1]);
        __builtin_nontemporal_store(q2, (long long*)&pl[pl2]);
        __builtin_nontemporal_store(q3, (long long*)&pl[pl3]);
        return;
    }
    // ---------- gemm path ----------
    int gid = blockIdx.x - blockIdx.x / 13 - 1;
    constexpr int ROWS = 256 / FO;
    constexpr int XS = FI + 1;
    __shared__ float Wu[FI * FO], Wd[FI * FO], Wp[FI * FO];
    __shared__ float xs[ROWS * XS];
    int tid = threadIdx.x;
    for (int i = tid; i < FI * FO; i += 256) {
        Wu[i] = uW[i];
        Wd[i] = dW[i];
        Wp[i] = pW[i];
    }
    int row0 = gid * ROWS;
    for (int i = tid; i < ROWS * FI; i += 256) {
        int r = i / FI, k = i - r * FI;
        int gr = row0 + r;
        xs[r * XS + k] = (gr < N_) ? x[(size_t)gr * FI + k] : 0.f;
    }
    __syncthreads();
    int r = tid / FO, j = tid - (tid / FO) * FO;
    int grow = row0 + r;
    float au = 0.f, ad = 0.f, ap = 0.f;
    #pragma unroll
    for (int k = 0; k < FI; ++k) {
        float xv = xs[r * XS + k];
        au = fmaf(xv, Wu[k * FO + j], au);
        ad = fmaf(xv, Wd[k * FO + j], ad);
        ap = fmaf(xv, Wp[k * FO + j], ap);
    }
    if (grow < N_) {
        HU[(size_t)grow * FO + j] = __float2half(au);
        HD[(size_t)grow * FO + j] = __float2half(ad);
        HP[(size_t)grow * FO + j] = __float2half(ap);
    }
    float vsu = au * uas[j], vdu = au * uad[j];
    float vsd = ad * das[j], vdd = ad * dad[j];
    #pragma unroll
    for (int m = FO / 2; m >= 1; m >>= 1) {
        vsu += __shfl_xor(vsu, m, FO);
        vdu += __shfl_xor(vdu, m, FO);
        vsd += __shfl_xor(vsd, m, FO);
        vdd += __shfl_xor(vdd, m, FO);
    }
    if (j == 0 && grow < N_) {
        ssu[grow] = vsu; sdu[grow] = vdu;
        ssd[grow] = vsd; sdd[grow] = vdd;
    }
}

// ---------------- fused dense (standalone, layers 2-4) ----------------

template <int FI, int FO>
__global__ __launch_bounds__(256) void gemm3_k(const float* __restrict__ x,
                                               const float* __restrict__ uW, const float* __restrict__ uas,
                                               const float* __restrict__ uad,
                                               const float* __restrict__ dW, const float* __restrict__ das,
                                               const float* __restrict__ dad,
                                               const float* __restrict__ pW,
                                               __half* __restrict__ HU, __half* __restrict__ HD,
                                               __half* __restrict__ HP,
                                               float* __restrict__ ssu, float* __restrict__ sdu,
                                               float* __restrict__ ssd, float* __restrict__ sdd) {
    constexpr int ROWS = 256 / FO;
    constexpr int XS = FI + 1;
    __shared__ float Wu[FI * FO], Wd[FI * FO], Wp[FI * FO];
    __shared__ float xs[ROWS * XS];
    int tid = threadIdx.x;
    for (int i = tid; i < FI * FO; i += 256) {
        Wu[i] = uW[i];
        Wd[i] = dW[i];
        Wp[i] = pW[i];
    }
    int row0 = blockIdx.x * ROWS;
    for (int i = tid; i < ROWS * FI; i += 256) {
        int r = i / FI, k = i - r * FI;
        int gr = row0 + r;
        xs[r * XS + k] = (gr < N_) ? x[(size_t)gr * FI + k] : 0.f;
    }
    __syncthreads();
    int r = tid / FO, j = tid - (tid / FO) * FO;
    int grow = row0 + r;
    float au = 0.f, ad = 0.f, ap = 0.f;
    #pragma unroll
    for (int k = 0; k < FI; ++k) {
        float xv = xs[r * XS + k];
        au = fmaf(xv, Wu[k * FO + j], au);
        ad = fmaf(xv, Wd[k * FO + j], ad);
        ap = fmaf(xv, Wp[k * FO + j], ap);
    }
    if (grow < N_) {
        HU[(size_t)grow * FO + j] = __float2half(au);
        HD[(size_t)grow * FO + j] = __float2half(ad);
        HP[(size_t)grow * FO + j] = __float2half(ap);
    }
    float vsu = au * uas[j], vdu = au * uad[j];
    float vsd = ad * das[j], vdd = ad * dad[j];
    #pragma unroll
    for (int m = FO / 2; m >= 1; m >>= 1) {
        vsu += __shfl_xor(vsu, m, FO);
        vdu += __shfl_xor(vdu, m, FO);
        vsd += __shfl_xor(vsd, m, FO);
        vdd += __shfl_xor(vdd, m, FO);
    }
    if (j == 0 && grow < N_) {
        ssu[grow] = vsu; sdu[grow] = vdu;
        ssd[grow] = vsd; sdd[grow] = vdd;
    }
}

// ---------------- wave-per-row fused gather (u + d + p) ----------------
// lane = slot*LPR + fs; SLOTS edges gathered per wave instruction.
// Feature accumulators stay lane-partial until one final slot-reduction
// (softmax normalization is linear in the partial sums); only z is
// reduced per GAT branch. CU/CD/PL are rebased to [0,NNZ) each.

template <int FO>
__global__ __launch_bounds__(256) void gather3_k(const int* __restrict__ rptr,
                                                 const int* __restrict__ cols_u,
                                                 const int* __restrict__ cols_d,
                                                 const int2* __restrict__ pl,
                                                 const __half* __restrict__ HU,
                                                 const __half* __restrict__ HD,
                                                 const __half* __restrict__ HP,
                                                 const float* __restrict__ ssu, const float* __restrict__ sdu,
                                                 const float* __restrict__ ssd, const float* __restrict__ sdd,
                                                 float* __restrict__ xout) {
    constexpr int LPR = FO / 8;      // lanes per row-slice (8 feats/lane, fp16 16B)
    constexpr int SLOTS = 64 / LPR;  // edge slots per wave
    int lane = threadIdx.x & 63;
    int wv = threadIdx.x >> 6;
    int fs = lane & (LPR - 1);
    int slot = lane / LPR;
    int r = blockIdx.x * 4 + wv;
    if (r >= N_) return;

    float out[8];
    #pragma unroll
    for (int k = 0; k < 8; ++k) out[k] = 0.f;

    // ---- GAT branches (u then d) ----
    #pragma unroll
    for (int br = 0; br < 2; ++br) {
        const int* cols = br == 0 ? cols_u : cols_d;
        const __half* H = br == 0 ? HU : HD;
        const float* sdv = br == 0 ? sdu : sdd;
        const float* ssv = br == 0 ? ssu : ssd;
        int base = br == 0 ? 0 : N_;
        int boff = br == 0 ? 0 : NNZ_;        // rebase into cols[0,NNZ)
        int b = rptr[base + r] - boff, e = rptr[base + r + 1] - boff;
        float s_row = ssv[r];
        float acc[8];
        #pragma unroll
        for (int k = 0; k < 8; ++k) acc[k] = 0.f;
        float z = 0.f;
        for (int p0 = b; p0 < e; p0 += SLOTS) {
            int p = p0 + slot;
            bool valid = p < e;
            int pc = valid ? p : e - 1;
            int c = cols[pc];
            float g = s_row + sdv[c];
            g = g > 0.f ? g : 0.2f * g;
            float w = valid ? __expf(g) : 0.f;
            z += w;
            const float4 hv = *reinterpret_cast<const float4*>(H + (size_t)c * FO + fs * 8);
            const __half2* h2 = reinterpret_cast<const __half2*>(&hv);
            #pragma unroll
            for (int k = 0; k < 4; ++k) {
                float2 f = __half22float2(h2[k]);
                acc[2 * k]     = fmaf(w, f.x, acc[2 * k]);
                acc[2 * k + 1] = fmaf(w, f.y, acc[2 * k + 1]);
            }
        }
        #pragma unroll
        for (int m = LPR; m < 64; m <<= 1) z += __shfl_xor(z, m);
        float inv = 1.f / (z + 1e-16f);
        #pragma unroll
        for (int k = 0; k < 8; ++k) out[k] = fmaf(acc[k], inv, out[k]);
    }

    // ---- p branch (packed col+val, rebased to [0,NNZ)) ----
    {
        int b = rptr[2 * N_ + r] - 2 * NNZ_, e = rptr[2 * N_ + r + 1] - 2 * NNZ_;
        for (int p0 = b; p0 < e; p0 += SLOTS) {
            int p = p0 + slot;
            bool valid = p < e;
            int pc = valid ? p : e - 1;
            int2 cv = pl[pc];
            int c = cv.x;
            float w = valid ? __int_as_float(cv.y) : 0.f;
            const float4 hv = *reinterpret_cast<const float4*>(HP + (size_t)c * FO + fs * 8);
            const __half2* h2 = reinterpret_cast<const __half2*>(&hv);
            #pragma unroll
            for (int k = 0; k < 4; ++k) {
                float2 f = __half22float2(h2[k]);
                out[2 * k]     = fmaf(w, f.x, out[2 * k]);
                out[2 * k + 1] = fmaf(w, f.y, out[2 * k + 1]);
            }
        }
    }

    // ---- final slot-reduction + relu + store ----
    #pragma unroll
    for (int k = 0; k < 8; ++k) {
        #pragma unroll
        for (int m = LPR; m < 64; m <<= 1) out[k] += __shfl_xor(out[k], m);
    }
    if (slot == 0) {
        float4 o0 = make_float4(fmaxf(out[0], 0.f), fmaxf(out[1], 0.f),
                                fmaxf(out[2], 0.f), fmaxf(out[3], 0.f));
        float4 o1 = make_float4(fmaxf(out[4], 0.f), fmaxf(out[5], 0.f),
                                fmaxf(out[6], 0.f), fmaxf(out[7], 0.f));
        float* op = xout + (size_t)r * FO + fs * 8;
        *reinterpret_cast<float4*>(op) = o0;
        *reinterpret_cast<float4*>(op + 4) = o1;
    }
}

// ---------------- pooling + softmax ----------------

__global__ __launch_bounds__(256) void pool_k(const float* __restrict__ x, const int* __restrict__ batch,
                                              float* __restrict__ out) {
    int g = blockIdx.x;
    __shared__ float part[256];
    __shared__ int sse[2];
    if (threadIdx.x < 2) {
        int target = g + threadIdx.x;
        int lo = 0, hi = N_;
        while (lo < hi) {
            int mid = (lo + hi) >> 1;
            if (batch[mid] < target) lo = mid + 1; else hi = mid;
        }
        sse[threadIdx.x] = lo;
    }
    __syncthreads();
    int s = sse[0], e = sse[1];
    int f = threadIdx.x % 8;
    float acc = 0.f;
    for (int i = s + threadIdx.x / 8; i < e; i += 32) acc += fabsf(x[(size_t)i * 8 + f]);
    part[threadIdx.x] = acc;
    __syncthreads();
    if (threadIdx.x < 8) {
        float t = 0.f;
        #pragma unroll
        for (int k = 0; k < 32; ++k) t += part[k * 8 + f];
        float cnt = (float)(e - s);
        part[f] = t / fmaxf(cnt, 1.0f);
    }
    __syncthreads();
    if (threadIdx.x == 0) {
        float m = part[0];
        for (int j = 1; j < 8; ++j) m = fmaxf(m, part[j]);
        float zs = 0.f;
        float ex[8];
        for (int j = 0; j < 8; ++j) { ex[j] = __expf(part[j] - m); zs += ex[j]; }
        for (int j = 0; j < 8; ++j) out[g * 8 + j] = ex[j] / zs;
    }
}

// ---------------- drivers ----------------

template <int FI, int FO>
static void run_layer(const float* xin, float* xout, const float* const* W,
                      __half* HU, __half* HD, __half* HP,
                      float* SSU, float* SDU, float* SSD, float* SDD,
                      const int* PTR, const int* CU, const int* CD, const int2* PL,
                      hipStream_t stream) {
    // W = {pW, uW, uas, uad, dW, das, dad}
    constexpr int ROWS = 256 / FO;
    gemm3_k<FI, FO><<<(N_ + ROWS - 1) / ROWS, 256, 0, stream>>>(
        xin, W[1], W[2], W[3], W[4], W[5], W[6], W[0],
        HU, HD, HP, SSU, SDU, SSD, SDD);
    gather3_k<FO><<<(N_ + 3) / 4, 256, 0, stream>>>(
        PTR, CU, CD, PL, HU, HD, HP, SSU, SDU, SSD, SDD, xout);
}

extern "C" void kernel_launch(void* const* d_in, const int* in_sizes, int n_in, void* d_out,
                              int out_size, void* d_ws, size_t ws_size, hipStream_t stream) {
    (void)in_sizes; (void)n_in; (void)out_size; (void)ws_size;
    const float* x1     = (const float*)d_in[0];
    const int*   l1_idx = (const int*)d_in[29];
    const float* l1_val = (const float*)d_in[30];
    const int*   lu_idx = (const int*)d_in[31];
    const int*   ld_idx = (const int*)d_in[32];
    const int*   batch1 = (const int*)d_in[33];
    float* out = (float*)d_out;

    char* w = (char*)d_ws;
    size_t off = 0;
    auto alloc = [&](size_t bytes) -> char* {
        char* p = w + off;
        off = (off + bytes + 255) & ~(size_t)255;
        return p;
    };
    float*  X    = (float*)alloc((size_t)N_ * 32 * 4);   // in-place layer state
    __half* HU   = (__half*)alloc((size_t)N_ * 32 * 2);
    __half* HD   = (__half*)alloc((size_t)N_ * 32 * 2);
    __half* HP   = (__half*)alloc((size_t)N_ * 32 * 2);
    float*  SSU  = (float*)alloc((size_t)N_ * 4);
    float*  SDU  = (float*)alloc((size_t)N_ * 4);
    float*  SSD  = (float*)alloc((size_t)N_ * 4);
    float*  SDD  = (float*)alloc((size_t)N_ * 4);
    int*    PTR  = (int*)alloc((size_t)(3 * N_ + 1) * 4);
    int*    DEG  = (int*)alloc((size_t)3 * N_ * 4);
    int*    BSUM = (int*)alloc((size_t)1024 * 4);
    int*    TICK = (int*)alloc((size_t)3 * NNZ_ * 4);
    int*    CU   = (int*)alloc((size_t)NNZ_ * 4);
    int*    CD   = (int*)alloc((size_t)NNZ_ * 4);
    int2*   PL   = (int2*)alloc((size_t)NNZ_ * 8);

    const float* W0[7] = {(const float*)d_in[1], (const float*)d_in[2], (const float*)d_in[3],
                          (const float*)d_in[4], (const float*)d_in[5], (const float*)d_in[6],
                          (const float*)d_in[7]};
    const float* W1[7] = {(const float*)d_in[8],  (const float*)d_in[9],  (const float*)d_in[10],
                          (const float*)d_in[11], (const float*)d_in[12], (const float*)d_in[13],
                          (const float*)d_in[14]};
    const float* W2[7] = {(const float*)d_in[15], (const float*)d_in[16], (const float*)d_in[17],
                          (const float*)d_in[18], (const float*)d_in[19], (const float*)d_in[20],
                          (const float*)d_in[21]};
    const float* W3[7] = {(const float*)d_in[22], (const float*)d_in[23], (const float*)d_in[24],
                          (const float*)d_in[25], (const float*)d_in[26], (const float*)d_in[27],
                          (const float*)d_in[28]};

    // ---- CSR build (layer-invariant; reused 4x) ----
    hipMemsetAsync(DEG, 0, (size_t)3 * N_ * 4, stream);
    constexpr int QBL = (NNZ_ / 4 + 255) / 256;   // 1954 scatter blocks
    hist_k<<<QBL, 256, 0, stream>>>(lu_idx, ld_idx, l1_idx, DEG, TICK);
    int n3 = 3 * N_;
    int nb = (n3 + 1023) / 1024;
    scan1_k<<<nb, 256, 0, stream>>>(DEG, PTR, BSUM, n3);
    scan2_k<<<1, 256, 0, stream>>>(BSUM, nb, PTR + n3);
    scan3_k<<<nb, 256, 0, stream>>>(PTR, BSUM, n3);

    // ---- scatter interleaved with layer-1 GEMM (1:13 block roles) ----
    {
        constexpr int T = 27100;  // ceil(T/13)=2085 >= QBL scatter roles; T-2085 >= 25000 gemm roles
        scat_gemm_k<64, 32, QBL><<<T, 256, 0, stream>>>(
            lu_idx, ld_idx, l1_idx, l1_val, PTR, TICK, CU, CD, PL,
            x1, W0[1], W0[2], W0[3], W0[4], W0[5], W0[6], W0[0],
            HU, HD, HP, SSU, SDU, SSD, SDD);
    }
    gather3_k<32><<<(N_ + 3) / 4, 256, 0, stream>>>(
        PTR, CU, CD, PL, HU, HD, HP, SSU, SDU, SSD, SDD, X);

    // ---- layers 2-4 ----
    run_layer<32, 32>(X, X, W1, HU, HD, HP, SSU, SDU, SSD, SDD, PTR, CU, CD, PL, stream);
    run_layer<32, 32>(X, X, W2, HU, HD, HP, SSU, SDU, SSD, SDD, PTR, CU, CD, PL, stream);
    run_layer<32, 8>(X, X, W3, HU, HD, HP, SSU, SDU, SSD, SDD, PTR, CU, CD, PL, stream);

    // ---- global mean pool of |x| + row softmax ----
    pool_k<<<G_, 256, 0, stream>>>(X, batch1, out);
}